// Round 17
// baseline (300.497 us; speedup 1.0000x reference)
//
#include <hip/hip_runtime.h>
#include <hip/hip_bf16.h>

#define NCH 64
#define NEL 10
#define NCHUNK 192
#define NSTEP 48
#define NROWS 24576          // 16 o * 192 units * 8 jj (shorts per ec slice)

#define WS_OFFS   0
#define WS_LIST   1024
#define WS_W      2097152    // 640 * 24576 * 2B = 31.46 MB

typedef __attribute__((ext_vector_type(8))) short  short8v;
typedef __attribute__((ext_vector_type(4))) float  float4v;
typedef __attribute__((ext_vector_type(4))) int    int4v;

__host__ __device__ constexpr int PJF(int p) { int j = 0; while (p >= j + 1) { p -= j + 1; ++j; } return j; }
__host__ __device__ constexpr int PIF(int p) { int j = 0; while (p >= j + 1) { p -= j + 1; ++j; } return p; }
__host__ __device__ constexpr int PJH(int p) { int j = 8; while (p >= j + 1) { p -= j + 1; ++j; } return j; }
__host__ __device__ constexpr int PIH(int p) { int j = 8; while (p >= j + 1) { p -= j + 1; ++j; } return p; }
// quad-pair decode, i-major (matches k_bgemm tail rows)
__host__ __device__ constexpr int QIc(int r) { int p = r, i = 0; while (p >= 16 - i) { p -= 16 - i; ++i; } return i; }
__host__ __device__ constexpr int QJc(int r) { int p = r, i = 0; while (p >= 16 - i) { p -= 16 - i; ++i; } return i + p; }

__device__ __forceinline__ unsigned int f_to_bf16u(float f) {
  union { float f; unsigned int i; } v; v.f = f;
  unsigned int x = v.i;
  unsigned int r = (x + 0x7fffu + ((x >> 16) & 1u)) >> 16;
  return r & 0xffffu;
}

// tail monomial for flat spec R = (KK-43)*32 + g*8 + jj — all indices compile-time
template<int R> __device__ __forceinline__ float tailprod(const float xr[16]) {
  if constexpr (R < 136)      return xr[QIc(R)] * xr[QJc(R)];   // quad
  else if constexpr (R < 152) return xr[R - 136];               // linear (x * 1.0)
  else                        return 0.f;                       // pad (B is zero there too)
}
__device__ __forceinline__ float tail_sel(float c0, float c1, float c2, float c3,
                                          bool g1, bool odd) {
  float mE = g1 ? c1 : c0;
  float mO = g1 ? c3 : c2;
  return odd ? mO : mE;
}

// ---- kernel 1: fused pack + GEMM (R8/R14 version, proven fastest — byte-identical) ----
__global__ __launch_bounds__(256) void k_bgemm(const float* __restrict__ U3,
                                               const float* __restrict__ U2,
                                               const float* __restrict__ U1,
                                               const float* __restrict__ w3,
                                               const float* __restrict__ w2,
                                               const float* __restrict__ w1,
                                               const int* __restrict__ idx,
                                               unsigned short* __restrict__ W,
                                               int* __restrict__ ws_offs,
                                               int* __restrict__ ws_list) {
  __shared__ unsigned short sU[256 * 32];   // 16384 B: packed A rows (local row = t)
  __shared__ unsigned short sWt[64 * 32];   // 4096 B: wallT[c][k] for this e
  __shared__ char sLT[4][2048];             // per-wave transpose buffers
  __shared__ int cnt[NEL];
  __shared__ int base[NEL + 1];
  int b = blockIdx.x;
  int t = threadIdx.x;

  if (b == 960) {                      // node bucketing: 256 threads x 4 nodes
    if (t < NEL) cnt[t] = 0;
    __syncthreads();
    int mye[4], myp[4];
#pragma unroll
    for (int k = 0; k < 4; ++k) {
      int n = t + k * 256;
      int e = idx[n];
      mye[k] = e;
      myp[k] = atomicAdd(&cnt[e], 1);
    }
    __syncthreads();
    if (t == 0) {
      int a = 0;
      for (int i = 0; i < NEL; ++i) { base[i] = a; a += cnt[i]; }
      base[NEL] = a;
    }
    __syncthreads();
#pragma unroll
    for (int k = 0; k < 4; ++k) ws_list[base[mye[k]] + myp[k]] = t + k * 256;
    if (t <= NEL) ws_offs[t] = base[t];
    return;
  }

  int e = b / 96, rb = b - e * 96;

  // ---- phase 1: pack this block's 256 A rows into sU ----
  {
    int row = rb * 256 + t;
    int o = row / 1536;
    int rem = row - o * 1536;
    int u = rem >> 3, jj = rem & 7;
    int n = u ^ (o & 7);               // inverse of the baked swizzle (involution)
#pragma unroll
    for (int kq = 0; kq < 4; ++kq) {
      float v[8] = {0.f, 0.f, 0.f, 0.f, 0.f, 0.f, 0.f, 0.f};
      if (n < 172) {                   // cubic rows: k 0..15 live
        int ci, cj, h;
        if (n < 72) { int p = n >> 1; h = n & 1; int j = 0; while (p >= j + 1) { p -= j + 1; ++j; } ci = p; cj = j; }
        else        { int p = n - 72; h = 1;     int j = 8; while (p >= j + 1) { p -= j + 1; ++j; } ci = p; cj = j; }
        int l = h * 8 + jj;
        if (kq < 2 && l >= cj) {
          const float* line = U3 + ((((size_t)o * 16 + ci) * 16 + cj) * 16 + l) * 16 + kq * 8;
          float4 q0 = *(const float4*)line;
          float4 q1 = *(const float4*)(line + 4);
          float mult = (ci == cj) ? (cj == l ? 1.f : 3.f) : (cj == l ? 3.f : 6.f);
          v[0] = q0.x * mult; v[1] = q0.y * mult; v[2] = q0.z * mult; v[3] = q0.w * mult;
          v[4] = q1.x * mult; v[5] = q1.y * mult; v[6] = q1.z * mult; v[7] = q1.w * mult;
        }
      } else {                         // tail rows
        int r = (n - 172) * 8 + jj;
        if (kq == 2 && r < 136) {      // quad: k 16..23
          int p = r, i2 = 0; while (p >= 16 - i2) { p -= 16 - i2; ++i2; }
          int a = i2, bb = i2 + p;
          const float* line = U2 + (((o * 16 + a) * 16) + bb) * 8;
          float4 q0 = *(const float4*)line;
          float4 q1 = *(const float4*)(line + 4);
          float sc = (a == bb) ? 1.f : 2.f;
          v[0] = q0.x * sc; v[1] = q0.y * sc; v[2] = q0.z * sc; v[3] = q0.w * sc;
          v[4] = q1.x * sc; v[5] = q1.y * sc; v[6] = q1.z * sc; v[7] = q1.w * sc;
        } else if (kq == 3 && r >= 136 && r < 152) {  // linear: k 24..27
          int a = r - 136;
          float4 q0 = *(const float4*)(U1 + (o * 16 + a) * 4);
          v[0] = q0.x; v[1] = q0.y; v[2] = q0.z; v[3] = q0.w;
        }
      }
      uint4 st;
      st.x = f_to_bf16u(v[0]) | (f_to_bf16u(v[1]) << 16);
      st.y = f_to_bf16u(v[2]) | (f_to_bf16u(v[3]) << 16);
      st.z = f_to_bf16u(v[4]) | (f_to_bf16u(v[5]) << 16);
      st.w = f_to_bf16u(v[6]) | (f_to_bf16u(v[7]) << 16);
      *(uint4*)(&sU[t * 32 + kq * 8]) = st;
    }
  }
  // ---- phase 1b: wallT slice for this e ----
  {
    int c = t & 63, kg = t >> 6;       // kg 0..3, 8 k each
    unsigned int pk[4];
#pragma unroll
    for (int hh = 0; hh < 4; ++hh) {
      int k0 = kg * 8 + hh * 2;
      float f0, f1;
      int k = k0;
      f0 = (k < 16) ? w3[(e * 16 + k) * NCH + c]
         : (k < 24) ? w2[(e * 8 + (k - 16)) * NCH + c]
         : (k < 28) ? w1[(e * 4 + (k - 24)) * NCH + c] : 0.f;
      k = k0 + 1;
      f1 = (k < 16) ? w3[(e * 16 + k) * NCH + c]
         : (k < 24) ? w2[(e * 8 + (k - 16)) * NCH + c]
         : (k < 28) ? w1[(e * 4 + (k - 24)) * NCH + c] : 0.f;
      pk[hh] = f_to_bf16u(f0) | (f_to_bf16u(f1) << 16);
    }
    uint4 st = {pk[0], pk[1], pk[2], pk[3]};
    *(uint4*)(&sWt[c * 32 + kg * 8]) = st;
  }
  __syncthreads();

  // ---- phase 2: GEMM + transposed coalesced stores ----
  int w = t >> 6, lane = t & 63;
  int rc = lane & 15, g = lane >> 4;
  int c = w * 16 + rc;
  short8v bv = *(const short8v*)(sWt + c * 32 + g * 8);
  char* wb = &sLT[w][0];
  int c_r = lane >> 2, q = lane & 3;
  int woff = rc * 128 + ((g * 8) ^ ((rc & 7) << 4));        // + rt2*32 per tile
  int roff0 = c_r * 128 + ((q * 16) ^ ((c_r & 7) << 4));
  int roff1 = c_r * 128 + (((64 + q * 16)) ^ ((c_r & 7) << 4));
  unsigned short* gcol = W + ((size_t)(e * 64 + w * 16 + c_r)) * NROWS + rb * 256;

#pragma unroll 1
  for (int grp = 0; grp < 4; ++grp) {
#pragma unroll
    for (int rt2 = 0; rt2 < 4; ++rt2) {
      int rowL = (grp * 4 + rt2) * 16 + rc;
      short8v av = *(const short8v*)(sU + rowL * 32 + g * 8);
      float4v acc = {0.f, 0.f, 0.f, 0.f};
      acc = __builtin_amdgcn_mfma_f32_16x16x32_bf16(av, bv, acc, 0, 0, 0);
      unsigned int lo, hi;
      asm("v_cvt_pk_bf16_f32 %0, %1, %2" : "=v"(lo) : "v"(acc[0]), "v"(acc[1]));
      asm("v_cvt_pk_bf16_f32 %0, %1, %2" : "=v"(hi) : "v"(acc[2]), "v"(acc[3]));
      uint2 pk = {lo, hi};             // rows g*4..g*4+3 of tile rt2, column c
      *(uint2*)(wb + (woff ^ (rt2 * 32))) = pk;
    }
    uint4 u0 = *(const uint4*)(wb + roff0);
    uint4 u1 = *(const uint4*)(wb + roff1);
    unsigned short* gp = gcol + grp * 64;
    *(uint4*)(gp + q * 8) = u0;        // rows grp*64 + q*8..+7      (64B x 16 c segs)
    *(uint4*)(gp + 32 + q * 8) = u1;   // rows grp*64 + 32 + q*8..+7
  }
}

// ---- kernel 2: MFMA main — R14 structure, register-only tail (no sX/sT LDS) ----
// LDS = sB only (49152 B) -> 3 blocks/CU; __launch_bounds__(512,6) caps VGPR <= 85.
// Tail monomials computed from the lane's own xr[] with compile-time indices and the
// H1-proven selG1/selOdd 4-candidate select — f32 products, bit-identical to R14.
#define PACK_MFMA(M0, M1, M2, M3, M4, M5, M6, M7, KK, ACC) { \
  int b0, b1, b2, b3; \
  asm("v_cvt_pk_bf16_f32 %0, %1, %2" : "=v"(b0) : "v"(M0), "v"(M1)); \
  asm("v_cvt_pk_bf16_f32 %0, %1, %2" : "=v"(b1) : "v"(M2), "v"(M3)); \
  asm("v_cvt_pk_bf16_f32 %0, %1, %2" : "=v"(b2) : "v"(M4), "v"(M5)); \
  asm("v_cvt_pk_bf16_f32 %0, %1, %2" : "=v"(b3) : "v"(M6), "v"(M7)); \
  int4v ai = {b0, b1, b2, b3}; \
  short8v av = __builtin_bit_cast(short8v, ai); \
  short8v bv = *(const short8v*)(bkL + (KK) * 1024); \
  ACC = __builtin_amdgcn_mfma_f32_16x16x32_bf16(av, bv, ACC, 0, 0, 0); \
}

#define FULL_STEP(KK, ACC) { \
  constexpr int iA = PIF(2 * (KK)), jA = PJF(2 * (KK)); \
  constexpr int iB = PIF(2 * (KK) + 1), jB = PJF(2 * (KK) + 1); \
  float xxA = xr[iA] * xr[jA]; \
  float xxB = xr[iB] * xr[jB]; \
  float xx = selOdd ? xxB : xxA; \
  PACK_MFMA(xx * xsF[0], xx * xsF[1], xx * xsF[2], xx * xsF[3], \
            xx * xsF[4], xx * xsF[5], xx * xsF[6], xx * xsF[7], KK, ACC) \
}

#define H1_STEP(KK, ACC) { \
  constexpr int q = 4 * ((KK) - 18); \
  constexpr int i0 = PIH(q), j0 = PJH(q); \
  constexpr int i1 = PIH(q + 1), j1 = PJH(q + 1); \
  constexpr int i2 = PIH(q + 2), j2 = PJH(q + 2); \
  constexpr int i3 = PIH(q + 3), j3 = PJH(q + 3); \
  float xx0 = xr[i0] * xr[j0], xx1 = xr[i1] * xr[j1]; \
  float xx2 = xr[i2] * xr[j2], xx3 = xr[i3] * xr[j3]; \
  float xxE = selG1 ? xx1 : xx0; \
  float xxO = selG1 ? xx3 : xx2; \
  float xx = selOdd ? xxO : xxE; \
  PACK_MFMA(xx * xr[8], xx * xr[9], xx * xr[10], xx * xr[11], \
            xx * xr[12], xx * xr[13], xx * xr[14], xx * xr[15], KK, ACC) \
}

#define TAIL_ONE(KK, JJ) \
  tail_sel(tailprod<((KK) - 43) * 32 + 0 * 8 + (JJ)>(xr), \
           tailprod<((KK) - 43) * 32 + 1 * 8 + (JJ)>(xr), \
           tailprod<((KK) - 43) * 32 + 2 * 8 + (JJ)>(xr), \
           tailprod<((KK) - 43) * 32 + 3 * 8 + (JJ)>(xr), selG1, selOdd)

#define TAIL_STEP(KK, ACC) { \
  float m0v = TAIL_ONE(KK, 0), m1v = TAIL_ONE(KK, 1); \
  float m2v = TAIL_ONE(KK, 2), m3v = TAIL_ONE(KK, 3); \
  float m4v = TAIL_ONE(KK, 4), m5v = TAIL_ONE(KK, 5); \
  float m6v = TAIL_ONE(KK, 6), m7v = TAIL_ONE(KK, 7); \
  PACK_MFMA(m0v, m1v, m2v, m3v, m4v, m5v, m6v, m7v, KK, ACC) \
}

__global__ __launch_bounds__(512, 6) void k_main(const float* __restrict__ x,
                                                 const int* __restrict__ offs,
                                                 const int* __restrict__ list,
                                                 const unsigned short* __restrict__ W,
                                                 float* __restrict__ out) {
  __shared__ unsigned short sB[NSTEP * 512];   // 49152 B, K-major after staged swizzle
  int t = threadIdx.x;
  int w = t >> 6, lane = t & 63;
  int rc = lane & 15;
  int g = lane >> 4;
  bool selOdd = g >= 2;
  bool selG1 = g & 1;

  int ec = blockIdx.x;
  int e = ec >> 6, c = ec & 63;

  // stage W[ec] -> K-major LDS via pre-swizzled global source + linear LDS dest
  {
    const uint4* Wg4 = (const uint4*)(W + (size_t)ec * NROWS);
    uint4* sB4 = (uint4*)sB;
#pragma unroll
    for (int s2 = 0; s2 < 6; ++s2) {
      int p = t + 512 * s2;            // LDS unit = KK*64 + g*16 + o
      int KK = p >> 6, gg = (p >> 4) & 3, oo = p & 15;
      int G = oo * 192 + ((4 * KK + gg) ^ (oo & 7));
      __builtin_amdgcn_global_load_lds(
          (const __attribute__((address_space(1))) void*)(Wg4 + G),
          (__attribute__((address_space(3))) void*)(sB4 + w * 64 + 512 * s2),
          16, 0, 0);
    }
  }
  __syncthreads();                     // drains vmcnt incl. global_load_lds

  int off = offs[e], nb = offs[e + 1] - off;
  int nt = (nb + 15) >> 4;
  const char* bkL = (const char*)sB + lane * 16;   // conflict-free base

  for (int tile = w; tile < nt; tile += 8) {
    int m = tile * 16 + rc;
    int node = list[off + (m < nb ? m : nb - 1)];
    float xr[16];
    {
      const float4* xp = (const float4*)(x + ((size_t)node * NCH + c) * 16);
      float4 q0 = xp[0], q1 = xp[1], q2 = xp[2], q3 = xp[3];
      xr[0] = q0.x; xr[1] = q0.y; xr[2] = q0.z; xr[3] = q0.w;
      xr[4] = q1.x; xr[5] = q1.y; xr[6] = q1.z; xr[7] = q1.w;
      xr[8] = q2.x; xr[9] = q2.y; xr[10] = q2.z; xr[11] = q2.w;
      xr[12] = q3.x; xr[13] = q3.y; xr[14] = q3.z; xr[15] = q3.w;
    }
    float xsF[8];
#pragma unroll
    for (int j = 0; j < 8; ++j) xsF[j] = selG1 ? xr[8 + j] : xr[j];

    float4v acc0 = {0.f, 0.f, 0.f, 0.f};
    float4v acc1 = {0.f, 0.f, 0.f, 0.f};
#define S2F(K) FULL_STEP(K, acc0) FULL_STEP((K) + 1, acc1)
#define S2H(K) H1_STEP(K, acc0) H1_STEP((K) + 1, acc1)
    S2F(0) S2F(2) S2F(4) S2F(6) S2F(8) S2F(10) S2F(12) S2F(14) S2F(16)
    S2H(18) S2H(20) S2H(22) S2H(24) S2H(26) S2H(28) S2H(30) S2H(32)
    S2H(34) S2H(36) S2H(38) S2H(40)
    H1_STEP(42, acc0)
    TAIL_STEP(43, acc1)
    TAIL_STEP(44, acc0) TAIL_STEP(45, acc1)
    TAIL_STEP(46, acc0) TAIL_STEP(47, acc1)
    float4v accs = acc0 + acc1;

#pragma unroll
    for (int r3 = 0; r3 < 4; ++r3) {
      int row = g * 4 + r3;
      int mrow = tile * 16 + row;
      if (mrow < nb) {
        int nd = __shfl(node, row);
        out[((size_t)nd * NCH + c) * 16 + rc] = accs[r3];
      }
    }
  }
}

extern "C" void kernel_launch(void* const* d_in, const int* in_sizes, int n_in,
                              void* d_out, int out_size, void* d_ws, size_t ws_size,
                              hipStream_t stream) {
  (void)in_sizes; (void)n_in; (void)out_size; (void)ws_size;
  const float* x   = (const float*)d_in[0];
  const int*   idx = (const int*)d_in[1];
  const float* w1  = (const float*)d_in[2];
  const float* w2  = (const float*)d_in[3];
  const float* w3  = (const float*)d_in[4];
  const float* U1  = (const float*)d_in[5];
  const float* U2  = (const float*)d_in[6];
  const float* U3  = (const float*)d_in[7];
  float* out = (float*)d_out;
  char* ws = (char*)d_ws;
  int* ws_offs = (int*)(ws + WS_OFFS);
  int* ws_list = (int*)(ws + WS_LIST);
  unsigned short* W = (unsigned short*)(ws + WS_W);

  hipLaunchKernelGGL(k_bgemm, dim3(961), dim3(256), 0, stream, U3, U2, U1, w3, w2, w1,
                     idx, W, ws_offs, ws_list);
  hipLaunchKernelGGL(k_main, dim3(640), dim3(512), 0, stream, x, ws_offs, ws_list, W, out);
}

// Round 18
// 247.185 us; speedup vs baseline: 1.2157x; 1.2157x over previous
//
#include <hip/hip_runtime.h>
#include <hip/hip_bf16.h>

#define NCH 64
#define NEL 10
#define NCHUNK 192
#define NSTEP 48
#define NROWS 24576          // 16 o * 192 units * 8 jj (shorts per ec slice)

#define WS_OFFS   0
#define WS_LIST   1024
#define WS_W      2097152    // 640 * 24576 * 2B = 31.46 MB

typedef __attribute__((ext_vector_type(8))) short  short8v;
typedef __attribute__((ext_vector_type(4))) float  float4v;
typedef __attribute__((ext_vector_type(4))) int    int4v;

__host__ __device__ constexpr int PJF(int p) { int j = 0; while (p >= j + 1) { p -= j + 1; ++j; } return j; }
__host__ __device__ constexpr int PIF(int p) { int j = 0; while (p >= j + 1) { p -= j + 1; ++j; } return p; }
__host__ __device__ constexpr int PJH(int p) { int j = 8; while (p >= j + 1) { p -= j + 1; ++j; } return j; }
__host__ __device__ constexpr int PIH(int p) { int j = 8; while (p >= j + 1) { p -= j + 1; ++j; } return p; }
// quad-pair decode, i-major (matches k_bgemm tail rows)
__host__ __device__ constexpr int QIc(int r) { int p = r, i = 0; while (p >= 16 - i) { p -= 16 - i; ++i; } return i; }
__host__ __device__ constexpr int QJc(int r) { int p = r, i = 0; while (p >= 16 - i) { p -= 16 - i; ++i; } return i + p; }

__device__ __forceinline__ unsigned int f_to_bf16u(float f) {
  union { float f; unsigned int i; } v; v.f = f;
  unsigned int x = v.i;
  unsigned int r = (x + 0x7fffu + ((x >> 16) & 1u)) >> 16;
  return r & 0xffffu;
}

// tail monomial for flat spec R = (KK-43)*32 + g*8 + jj — all indices compile-time
template<int R> __device__ __forceinline__ float tailprod(const float xr[16]) {
  if constexpr (R < 136)      return xr[QIc(R)] * xr[QJc(R)];   // quad
  else if constexpr (R < 152) return xr[R - 136];               // linear (x * 1.0)
  else                        return 0.f;                       // pad (B is zero there too)
}
__device__ __forceinline__ float tail_sel(float c0, float c1, float c2, float c3,
                                          bool g1, bool odd) {
  float mE = g1 ? c1 : c0;
  float mO = g1 ? c3 : c2;
  return odd ? mO : mE;
}

// ---- kernel 1: fused pack + GEMM (R8/R14 version, proven fastest — byte-identical) ----
__global__ __launch_bounds__(256) void k_bgemm(const float* __restrict__ U3,
                                               const float* __restrict__ U2,
                                               const float* __restrict__ U1,
                                               const float* __restrict__ w3,
                                               const float* __restrict__ w2,
                                               const float* __restrict__ w1,
                                               const int* __restrict__ idx,
                                               unsigned short* __restrict__ W,
                                               int* __restrict__ ws_offs,
                                               int* __restrict__ ws_list) {
  __shared__ unsigned short sU[256 * 32];   // 16384 B: packed A rows (local row = t)
  __shared__ unsigned short sWt[64 * 32];   // 4096 B: wallT[c][k] for this e
  __shared__ char sLT[4][2048];             // per-wave transpose buffers
  __shared__ int cnt[NEL];
  __shared__ int base[NEL + 1];
  int b = blockIdx.x;
  int t = threadIdx.x;

  if (b == 960) {                      // node bucketing: 256 threads x 4 nodes
    if (t < NEL) cnt[t] = 0;
    __syncthreads();
    int mye[4], myp[4];
#pragma unroll
    for (int k = 0; k < 4; ++k) {
      int n = t + k * 256;
      int e = idx[n];
      mye[k] = e;
      myp[k] = atomicAdd(&cnt[e], 1);
    }
    __syncthreads();
    if (t == 0) {
      int a = 0;
      for (int i = 0; i < NEL; ++i) { base[i] = a; a += cnt[i]; }
      base[NEL] = a;
    }
    __syncthreads();
#pragma unroll
    for (int k = 0; k < 4; ++k) ws_list[base[mye[k]] + myp[k]] = t + k * 256;
    if (t <= NEL) ws_offs[t] = base[t];
    return;
  }

  int e = b / 96, rb = b - e * 96;

  // ---- phase 1: pack this block's 256 A rows into sU ----
  {
    int row = rb * 256 + t;
    int o = row / 1536;
    int rem = row - o * 1536;
    int u = rem >> 3, jj = rem & 7;
    int n = u ^ (o & 7);               // inverse of the baked swizzle (involution)
#pragma unroll
    for (int kq = 0; kq < 4; ++kq) {
      float v[8] = {0.f, 0.f, 0.f, 0.f, 0.f, 0.f, 0.f, 0.f};
      if (n < 172) {                   // cubic rows: k 0..15 live
        int ci, cj, h;
        if (n < 72) { int p = n >> 1; h = n & 1; int j = 0; while (p >= j + 1) { p -= j + 1; ++j; } ci = p; cj = j; }
        else        { int p = n - 72; h = 1;     int j = 8; while (p >= j + 1) { p -= j + 1; ++j; } ci = p; cj = j; }
        int l = h * 8 + jj;
        if (kq < 2 && l >= cj) {
          const float* line = U3 + ((((size_t)o * 16 + ci) * 16 + cj) * 16 + l) * 16 + kq * 8;
          float4 q0 = *(const float4*)line;
          float4 q1 = *(const float4*)(line + 4);
          float mult = (ci == cj) ? (cj == l ? 1.f : 3.f) : (cj == l ? 3.f : 6.f);
          v[0] = q0.x * mult; v[1] = q0.y * mult; v[2] = q0.z * mult; v[3] = q0.w * mult;
          v[4] = q1.x * mult; v[5] = q1.y * mult; v[6] = q1.z * mult; v[7] = q1.w * mult;
        }
      } else {                         // tail rows
        int r = (n - 172) * 8 + jj;
        if (kq == 2 && r < 136) {      // quad: k 16..23
          int p = r, i2 = 0; while (p >= 16 - i2) { p -= 16 - i2; ++i2; }
          int a = i2, bb = i2 + p;
          const float* line = U2 + (((o * 16 + a) * 16) + bb) * 8;
          float4 q0 = *(const float4*)line;
          float4 q1 = *(const float4*)(line + 4);
          float sc = (a == bb) ? 1.f : 2.f;
          v[0] = q0.x * sc; v[1] = q0.y * sc; v[2] = q0.z * sc; v[3] = q0.w * sc;
          v[4] = q1.x * sc; v[5] = q1.y * sc; v[6] = q1.z * sc; v[7] = q1.w * sc;
        } else if (kq == 3 && r >= 136 && r < 152) {  // linear: k 24..27
          int a = r - 136;
          float4 q0 = *(const float4*)(U1 + (o * 16 + a) * 4);
          v[0] = q0.x; v[1] = q0.y; v[2] = q0.z; v[3] = q0.w;
        }
      }
      uint4 st;
      st.x = f_to_bf16u(v[0]) | (f_to_bf16u(v[1]) << 16);
      st.y = f_to_bf16u(v[2]) | (f_to_bf16u(v[3]) << 16);
      st.z = f_to_bf16u(v[4]) | (f_to_bf16u(v[5]) << 16);
      st.w = f_to_bf16u(v[6]) | (f_to_bf16u(v[7]) << 16);
      *(uint4*)(&sU[t * 32 + kq * 8]) = st;
    }
  }
  // ---- phase 1b: wallT slice for this e ----
  {
    int c = t & 63, kg = t >> 6;       // kg 0..3, 8 k each
    unsigned int pk[4];
#pragma unroll
    for (int hh = 0; hh < 4; ++hh) {
      int k0 = kg * 8 + hh * 2;
      float f0, f1;
      int k = k0;
      f0 = (k < 16) ? w3[(e * 16 + k) * NCH + c]
         : (k < 24) ? w2[(e * 8 + (k - 16)) * NCH + c]
         : (k < 28) ? w1[(e * 4 + (k - 24)) * NCH + c] : 0.f;
      k = k0 + 1;
      f1 = (k < 16) ? w3[(e * 16 + k) * NCH + c]
         : (k < 24) ? w2[(e * 8 + (k - 16)) * NCH + c]
         : (k < 28) ? w1[(e * 4 + (k - 24)) * NCH + c] : 0.f;
      pk[hh] = f_to_bf16u(f0) | (f_to_bf16u(f1) << 16);
    }
    uint4 st = {pk[0], pk[1], pk[2], pk[3]};
    *(uint4*)(&sWt[c * 32 + kg * 8]) = st;
  }
  __syncthreads();

  // ---- phase 2: GEMM + transposed coalesced stores ----
  int w = t >> 6, lane = t & 63;
  int rc = lane & 15, g = lane >> 4;
  int c = w * 16 + rc;
  short8v bv = *(const short8v*)(sWt + c * 32 + g * 8);
  char* wb = &sLT[w][0];
  int c_r = lane >> 2, q = lane & 3;
  int woff = rc * 128 + ((g * 8) ^ ((rc & 7) << 4));        // + rt2*32 per tile
  int roff0 = c_r * 128 + ((q * 16) ^ ((c_r & 7) << 4));
  int roff1 = c_r * 128 + (((64 + q * 16)) ^ ((c_r & 7) << 4));
  unsigned short* gcol = W + ((size_t)(e * 64 + w * 16 + c_r)) * NROWS + rb * 256;

#pragma unroll 1
  for (int grp = 0; grp < 4; ++grp) {
#pragma unroll
    for (int rt2 = 0; rt2 < 4; ++rt2) {
      int rowL = (grp * 4 + rt2) * 16 + rc;
      short8v av = *(const short8v*)(sU + rowL * 32 + g * 8);
      float4v acc = {0.f, 0.f, 0.f, 0.f};
      acc = __builtin_amdgcn_mfma_f32_16x16x32_bf16(av, bv, acc, 0, 0, 0);
      unsigned int lo, hi;
      asm("v_cvt_pk_bf16_f32 %0, %1, %2" : "=v"(lo) : "v"(acc[0]), "v"(acc[1]));
      asm("v_cvt_pk_bf16_f32 %0, %1, %2" : "=v"(hi) : "v"(acc[2]), "v"(acc[3]));
      uint2 pk = {lo, hi};             // rows g*4..g*4+3 of tile rt2, column c
      *(uint2*)(wb + (woff ^ (rt2 * 32))) = pk;
    }
    uint4 u0 = *(const uint4*)(wb + roff0);
    uint4 u1 = *(const uint4*)(wb + roff1);
    unsigned short* gp = gcol + grp * 64;
    *(uint4*)(gp + q * 8) = u0;        // rows grp*64 + q*8..+7      (64B x 16 c segs)
    *(uint4*)(gp + 32 + q * 8) = u1;   // rows grp*64 + 32 + q*8..+7
  }
}

// ---- kernel 2: MFMA main — R14 structure, register-only tail, (512,4) bounds ----
// LDS = sB only (49152 B). R17's (512,6) forced VGPR<=85 -> catastrophic scratch spill
// (VGPR=40, 466 MB scratch writes). (512,4) gives the 128-VGPR budget of the passing
// 41.0 µs R14 config; occupancy 2 blocks/CU (VGPR-capped — 3 blocks is unreachable).
#define PACK_MFMA(M0, M1, M2, M3, M4, M5, M6, M7, KK, ACC) { \
  int b0, b1, b2, b3; \
  asm("v_cvt_pk_bf16_f32 %0, %1, %2" : "=v"(b0) : "v"(M0), "v"(M1)); \
  asm("v_cvt_pk_bf16_f32 %0, %1, %2" : "=v"(b1) : "v"(M2), "v"(M3)); \
  asm("v_cvt_pk_bf16_f32 %0, %1, %2" : "=v"(b2) : "v"(M4), "v"(M5)); \
  asm("v_cvt_pk_bf16_f32 %0, %1, %2" : "=v"(b3) : "v"(M6), "v"(M7)); \
  int4v ai = {b0, b1, b2, b3}; \
  short8v av = __builtin_bit_cast(short8v, ai); \
  short8v bv = *(const short8v*)(bkL + (KK) * 1024); \
  ACC = __builtin_amdgcn_mfma_f32_16x16x32_bf16(av, bv, ACC, 0, 0, 0); \
}

#define FULL_STEP(KK, ACC) { \
  constexpr int iA = PIF(2 * (KK)), jA = PJF(2 * (KK)); \
  constexpr int iB = PIF(2 * (KK) + 1), jB = PJF(2 * (KK) + 1); \
  float xxA = xr[iA] * xr[jA]; \
  float xxB = xr[iB] * xr[jB]; \
  float xx = selOdd ? xxB : xxA; \
  PACK_MFMA(xx * xsF[0], xx * xsF[1], xx * xsF[2], xx * xsF[3], \
            xx * xsF[4], xx * xsF[5], xx * xsF[6], xx * xsF[7], KK, ACC) \
}

#define H1_STEP(KK, ACC) { \
  constexpr int q = 4 * ((KK) - 18); \
  constexpr int i0 = PIH(q), j0 = PJH(q); \
  constexpr int i1 = PIH(q + 1), j1 = PJH(q + 1); \
  constexpr int i2 = PIH(q + 2), j2 = PJH(q + 2); \
  constexpr int i3 = PIH(q + 3), j3 = PJH(q + 3); \
  float xx0 = xr[i0] * xr[j0], xx1 = xr[i1] * xr[j1]; \
  float xx2 = xr[i2] * xr[j2], xx3 = xr[i3] * xr[j3]; \
  float xxE = selG1 ? xx1 : xx0; \
  float xxO = selG1 ? xx3 : xx2; \
  float xx = selOdd ? xxO : xxE; \
  PACK_MFMA(xx * xr[8], xx * xr[9], xx * xr[10], xx * xr[11], \
            xx * xr[12], xx * xr[13], xx * xr[14], xx * xr[15], KK, ACC) \
}

#define TAIL_ONE(KK, JJ) \
  tail_sel(tailprod<((KK) - 43) * 32 + 0 * 8 + (JJ)>(xr), \
           tailprod<((KK) - 43) * 32 + 1 * 8 + (JJ)>(xr), \
           tailprod<((KK) - 43) * 32 + 2 * 8 + (JJ)>(xr), \
           tailprod<((KK) - 43) * 32 + 3 * 8 + (JJ)>(xr), selG1, selOdd)

#define TAIL_STEP(KK, ACC) { \
  float m0v = TAIL_ONE(KK, 0), m1v = TAIL_ONE(KK, 1); \
  float m2v = TAIL_ONE(KK, 2), m3v = TAIL_ONE(KK, 3); \
  float m4v = TAIL_ONE(KK, 4), m5v = TAIL_ONE(KK, 5); \
  float m6v = TAIL_ONE(KK, 6), m7v = TAIL_ONE(KK, 7); \
  PACK_MFMA(m0v, m1v, m2v, m3v, m4v, m5v, m6v, m7v, KK, ACC) \
}

__global__ __launch_bounds__(512, 4) void k_main(const float* __restrict__ x,
                                                 const int* __restrict__ offs,
                                                 const int* __restrict__ list,
                                                 const unsigned short* __restrict__ W,
                                                 float* __restrict__ out) {
  __shared__ unsigned short sB[NSTEP * 512];   // 49152 B, K-major after staged swizzle
  int t = threadIdx.x;
  int w = t >> 6, lane = t & 63;
  int rc = lane & 15;
  int g = lane >> 4;
  bool selOdd = g >= 2;
  bool selG1 = g & 1;

  int ec = blockIdx.x;
  int e = ec >> 6, c = ec & 63;

  // stage W[ec] -> K-major LDS via pre-swizzled global source + linear LDS dest
  {
    const uint4* Wg4 = (const uint4*)(W + (size_t)ec * NROWS);
    uint4* sB4 = (uint4*)sB;
#pragma unroll
    for (int s2 = 0; s2 < 6; ++s2) {
      int p = t + 512 * s2;            // LDS unit = KK*64 + g*16 + o
      int KK = p >> 6, gg = (p >> 4) & 3, oo = p & 15;
      int G = oo * 192 + ((4 * KK + gg) ^ (oo & 7));
      __builtin_amdgcn_global_load_lds(
          (const __attribute__((address_space(1))) void*)(Wg4 + G),
          (__attribute__((address_space(3))) void*)(sB4 + w * 64 + 512 * s2),
          16, 0, 0);
    }
  }
  __syncthreads();                     // drains vmcnt incl. global_load_lds

  int off = offs[e], nb = offs[e + 1] - off;
  int nt = (nb + 15) >> 4;
  const char* bkL = (const char*)sB + lane * 16;   // conflict-free base

  for (int tile = w; tile < nt; tile += 8) {
    int m = tile * 16 + rc;
    int node = list[off + (m < nb ? m : nb - 1)];
    float xr[16];
    {
      const float4* xp = (const float4*)(x + ((size_t)node * NCH + c) * 16);
      float4 q0 = xp[0], q1 = xp[1], q2 = xp[2], q3 = xp[3];
      xr[0] = q0.x; xr[1] = q0.y; xr[2] = q0.z; xr[3] = q0.w;
      xr[4] = q1.x; xr[5] = q1.y; xr[6] = q1.z; xr[7] = q1.w;
      xr[8] = q2.x; xr[9] = q2.y; xr[10] = q2.z; xr[11] = q2.w;
      xr[12] = q3.x; xr[13] = q3.y; xr[14] = q3.z; xr[15] = q3.w;
    }
    float xsF[8];
#pragma unroll
    for (int j = 0; j < 8; ++j) xsF[j] = selG1 ? xr[8 + j] : xr[j];

    float4v acc0 = {0.f, 0.f, 0.f, 0.f};
    float4v acc1 = {0.f, 0.f, 0.f, 0.f};
#define S2F(K) FULL_STEP(K, acc0) FULL_STEP((K) + 1, acc1)
#define S2H(K) H1_STEP(K, acc0) H1_STEP((K) + 1, acc1)
    S2F(0) S2F(2) S2F(4) S2F(6) S2F(8) S2F(10) S2F(12) S2F(14) S2F(16)
    S2H(18) S2H(20) S2H(22) S2H(24) S2H(26) S2H(28) S2H(30) S2H(32)
    S2H(34) S2H(36) S2H(38) S2H(40)
    H1_STEP(42, acc0)
    TAIL_STEP(43, acc1)
    TAIL_STEP(44, acc0) TAIL_STEP(45, acc1)
    TAIL_STEP(46, acc0) TAIL_STEP(47, acc1)
    float4v accs = acc0 + acc1;

#pragma unroll
    for (int r3 = 0; r3 < 4; ++r3) {
      int row = g * 4 + r3;
      int mrow = tile * 16 + row;
      if (mrow < nb) {
        int nd = __shfl(node, row);
        out[((size_t)nd * NCH + c) * 16 + rc] = accs[r3];
      }
    }
  }
}

extern "C" void kernel_launch(void* const* d_in, const int* in_sizes, int n_in,
                              void* d_out, int out_size, void* d_ws, size_t ws_size,
                              hipStream_t stream) {
  (void)in_sizes; (void)n_in; (void)out_size; (void)ws_size;
  const float* x   = (const float*)d_in[0];
  const int*   idx = (const int*)d_in[1];
  const float* w1  = (const float*)d_in[2];
  const float* w2  = (const float*)d_in[3];
  const float* w3  = (const float*)d_in[4];
  const float* U1  = (const float*)d_in[5];
  const float* U2  = (const float*)d_in[6];
  const float* U3  = (const float*)d_in[7];
  float* out = (float*)d_out;
  char* ws = (char*)d_ws;
  int* ws_offs = (int*)(ws + WS_OFFS);
  int* ws_list = (int*)(ws + WS_LIST);
  unsigned short* W = (unsigned short*)(ws + WS_W);

  hipLaunchKernelGGL(k_bgemm, dim3(961), dim3(256), 0, stream, U3, U2, U1, w3, w2, w1,
                     idx, W, ws_offs, ws_list);
  hipLaunchKernelGGL(k_main, dim3(640), dim3(512), 0, stream, x, ws_offs, ws_list, W, out);
}

// Round 19
// 40.573 us; speedup vs baseline: 7.4063x; 6.0924x over previous
//
#include <hip/hip_runtime.h>
#include <hip/hip_bf16.h>

#define NCH 64
#define NEL 10
#define NCHUNK 192
#define NSTEP 48
#define NROWS 24576          // 16 o * 192 units * 8 jj (shorts per ec slice)

#define WS_OFFS   0
#define WS_LIST   1024
#define WS_W      2097152    // 640 * 24576 * 2B = 31.46 MB

typedef __attribute__((ext_vector_type(8))) short  short8v;
typedef __attribute__((ext_vector_type(4))) float  float4v;
typedef __attribute__((ext_vector_type(4))) int    int4v;

__host__ __device__ constexpr int PJF(int p) { int j = 0; while (p >= j + 1) { p -= j + 1; ++j; } return j; }
__host__ __device__ constexpr int PIF(int p) { int j = 0; while (p >= j + 1) { p -= j + 1; ++j; } return p; }
__host__ __device__ constexpr int PJH(int p) { int j = 8; while (p >= j + 1) { p -= j + 1; ++j; } return j; }
__host__ __device__ constexpr int PIH(int p) { int j = 8; while (p >= j + 1) { p -= j + 1; ++j; } return p; }

__device__ __forceinline__ unsigned int f_to_bf16u(float f) {
  union { float f; unsigned int i; } v; v.f = f;
  unsigned int x = v.i;
  unsigned int r = (x + 0x7fffu + ((x >> 16) & 1u)) >> 16;
  return r & 0xffffu;
}

// ---- kernel 1: fused pack + GEMM (R8/R14 version, proven fastest — byte-identical) ----
__global__ __launch_bounds__(256) void k_bgemm(const float* __restrict__ U3,
                                               const float* __restrict__ U2,
                                               const float* __restrict__ U1,
                                               const float* __restrict__ w3,
                                               const float* __restrict__ w2,
                                               const float* __restrict__ w1,
                                               const int* __restrict__ idx,
                                               unsigned short* __restrict__ W,
                                               int* __restrict__ ws_offs,
                                               int* __restrict__ ws_list) {
  __shared__ unsigned short sU[256 * 32];   // 16384 B: packed A rows (local row = t)
  __shared__ unsigned short sWt[64 * 32];   // 4096 B: wallT[c][k] for this e
  __shared__ char sLT[4][2048];             // per-wave transpose buffers
  __shared__ int cnt[NEL];
  __shared__ int base[NEL + 1];
  int b = blockIdx.x;
  int t = threadIdx.x;

  if (b == 960) {                      // node bucketing: 256 threads x 4 nodes
    if (t < NEL) cnt[t] = 0;
    __syncthreads();
    int mye[4], myp[4];
#pragma unroll
    for (int k = 0; k < 4; ++k) {
      int n = t + k * 256;
      int e = idx[n];
      mye[k] = e;
      myp[k] = atomicAdd(&cnt[e], 1);
    }
    __syncthreads();
    if (t == 0) {
      int a = 0;
      for (int i = 0; i < NEL; ++i) { base[i] = a; a += cnt[i]; }
      base[NEL] = a;
    }
    __syncthreads();
#pragma unroll
    for (int k = 0; k < 4; ++k) ws_list[base[mye[k]] + myp[k]] = t + k * 256;
    if (t <= NEL) ws_offs[t] = base[t];
    return;
  }

  int e = b / 96, rb = b - e * 96;

  // ---- phase 1: pack this block's 256 A rows into sU ----
  {
    int row = rb * 256 + t;
    int o = row / 1536;
    int rem = row - o * 1536;
    int u = rem >> 3, jj = rem & 7;
    int n = u ^ (o & 7);               // inverse of the baked swizzle (involution)
#pragma unroll
    for (int kq = 0; kq < 4; ++kq) {
      float v[8] = {0.f, 0.f, 0.f, 0.f, 0.f, 0.f, 0.f, 0.f};
      if (n < 172) {                   // cubic rows: k 0..15 live
        int ci, cj, h;
        if (n < 72) { int p = n >> 1; h = n & 1; int j = 0; while (p >= j + 1) { p -= j + 1; ++j; } ci = p; cj = j; }
        else        { int p = n - 72; h = 1;     int j = 8; while (p >= j + 1) { p -= j + 1; ++j; } ci = p; cj = j; }
        int l = h * 8 + jj;
        if (kq < 2 && l >= cj) {
          const float* line = U3 + ((((size_t)o * 16 + ci) * 16 + cj) * 16 + l) * 16 + kq * 8;
          float4 q0 = *(const float4*)line;
          float4 q1 = *(const float4*)(line + 4);
          float mult = (ci == cj) ? (cj == l ? 1.f : 3.f) : (cj == l ? 3.f : 6.f);
          v[0] = q0.x * mult; v[1] = q0.y * mult; v[2] = q0.z * mult; v[3] = q0.w * mult;
          v[4] = q1.x * mult; v[5] = q1.y * mult; v[6] = q1.z * mult; v[7] = q1.w * mult;
        }
      } else {                         // tail rows
        int r = (n - 172) * 8 + jj;
        if (kq == 2 && r < 136) {      // quad: k 16..23
          int p = r, i2 = 0; while (p >= 16 - i2) { p -= 16 - i2; ++i2; }
          int a = i2, bb = i2 + p;
          const float* line = U2 + (((o * 16 + a) * 16) + bb) * 8;
          float4 q0 = *(const float4*)line;
          float4 q1 = *(const float4*)(line + 4);
          float sc = (a == bb) ? 1.f : 2.f;
          v[0] = q0.x * sc; v[1] = q0.y * sc; v[2] = q0.z * sc; v[3] = q0.w * sc;
          v[4] = q1.x * sc; v[5] = q1.y * sc; v[6] = q1.z * sc; v[7] = q1.w * sc;
        } else if (kq == 3 && r >= 136 && r < 152) {  // linear: k 24..27
          int a = r - 136;
          float4 q0 = *(const float4*)(U1 + (o * 16 + a) * 4);
          v[0] = q0.x; v[1] = q0.y; v[2] = q0.z; v[3] = q0.w;
        }
      }
      uint4 st;
      st.x = f_to_bf16u(v[0]) | (f_to_bf16u(v[1]) << 16);
      st.y = f_to_bf16u(v[2]) | (f_to_bf16u(v[3]) << 16);
      st.z = f_to_bf16u(v[4]) | (f_to_bf16u(v[5]) << 16);
      st.w = f_to_bf16u(v[6]) | (f_to_bf16u(v[7]) << 16);
      *(uint4*)(&sU[t * 32 + kq * 8]) = st;
    }
  }
  // ---- phase 1b: wallT slice for this e ----
  {
    int c = t & 63, kg = t >> 6;       // kg 0..3, 8 k each
    unsigned int pk[4];
#pragma unroll
    for (int hh = 0; hh < 4; ++hh) {
      int k0 = kg * 8 + hh * 2;
      float f0, f1;
      int k = k0;
      f0 = (k < 16) ? w3[(e * 16 + k) * NCH + c]
         : (k < 24) ? w2[(e * 8 + (k - 16)) * NCH + c]
         : (k < 28) ? w1[(e * 4 + (k - 24)) * NCH + c] : 0.f;
      k = k0 + 1;
      f1 = (k < 16) ? w3[(e * 16 + k) * NCH + c]
         : (k < 24) ? w2[(e * 8 + (k - 16)) * NCH + c]
         : (k < 28) ? w1[(e * 4 + (k - 24)) * NCH + c] : 0.f;
      pk[hh] = f_to_bf16u(f0) | (f_to_bf16u(f1) << 16);
    }
    uint4 st = {pk[0], pk[1], pk[2], pk[3]};
    *(uint4*)(&sWt[c * 32 + kg * 8]) = st;
  }
  __syncthreads();

  // ---- phase 2: GEMM + transposed coalesced stores ----
  int w = t >> 6, lane = t & 63;
  int rc = lane & 15, g = lane >> 4;
  int c = w * 16 + rc;
  short8v bv = *(const short8v*)(sWt + c * 32 + g * 8);
  char* wb = &sLT[w][0];
  int c_r = lane >> 2, q = lane & 3;
  int woff = rc * 128 + ((g * 8) ^ ((rc & 7) << 4));        // + rt2*32 per tile
  int roff0 = c_r * 128 + ((q * 16) ^ ((c_r & 7) << 4));
  int roff1 = c_r * 128 + (((64 + q * 16)) ^ ((c_r & 7) << 4));
  unsigned short* gcol = W + ((size_t)(e * 64 + w * 16 + c_r)) * NROWS + rb * 256;

#pragma unroll 1
  for (int grp = 0; grp < 4; ++grp) {
#pragma unroll
    for (int rt2 = 0; rt2 < 4; ++rt2) {
      int rowL = (grp * 4 + rt2) * 16 + rc;
      short8v av = *(const short8v*)(sU + rowL * 32 + g * 8);
      float4v acc = {0.f, 0.f, 0.f, 0.f};
      acc = __builtin_amdgcn_mfma_f32_16x16x32_bf16(av, bv, acc, 0, 0, 0);
      unsigned int lo, hi;
      asm("v_cvt_pk_bf16_f32 %0, %1, %2" : "=v"(lo) : "v"(acc[0]), "v"(acc[1]));
      asm("v_cvt_pk_bf16_f32 %0, %1, %2" : "=v"(hi) : "v"(acc[2]), "v"(acc[3]));
      uint2 pk = {lo, hi};             // rows g*4..g*4+3 of tile rt2, column c
      *(uint2*)(wb + (woff ^ (rt2 * 32))) = pk;
    }
    uint4 u0 = *(const uint4*)(wb + roff0);
    uint4 u1 = *(const uint4*)(wb + roff1);
    unsigned short* gp = gcol + grp * 64;
    *(uint4*)(gp + q * 8) = u0;        // rows grp*64 + q*8..+7      (64B x 16 c segs)
    *(uint4*)(gp + 32 + q * 8) = u1;   // rows grp*64 + 32 + q*8..+7
  }
}

// ---- kernel 2: MFMA main — pre-swizzled-source stage -> K-major LDS, conflict-free B reads ----
// Stage (m173 pattern): LDS dest linear (global_load_lds requirement); per-lane GLOBAL
// source G(p) = o*192 + ((4*KK+g)^(o&7)) for LDS unit p = KK*64 + g*16 + o. Result:
// B-fragment for step KK at lds + KK*1024 + lane*16 = 64 x 16B contiguous = 0 conflicts.
// Tail reads x from sX (f32) — keeps VGPR at 64 without spill (register-tail spills: R17/R18).
#define PACK_MFMA(M0, M1, M2, M3, M4, M5, M6, M7, KK, ACC) { \
  int b0, b1, b2, b3; \
  asm("v_cvt_pk_bf16_f32 %0, %1, %2" : "=v"(b0) : "v"(M0), "v"(M1)); \
  asm("v_cvt_pk_bf16_f32 %0, %1, %2" : "=v"(b1) : "v"(M2), "v"(M3)); \
  asm("v_cvt_pk_bf16_f32 %0, %1, %2" : "=v"(b2) : "v"(M4), "v"(M5)); \
  asm("v_cvt_pk_bf16_f32 %0, %1, %2" : "=v"(b3) : "v"(M6), "v"(M7)); \
  int4v ai = {b0, b1, b2, b3}; \
  short8v av = __builtin_bit_cast(short8v, ai); \
  short8v bv = *(const short8v*)(bkL + (KK) * 1024); \
  ACC = __builtin_amdgcn_mfma_f32_16x16x32_bf16(av, bv, ACC, 0, 0, 0); \
}

#define FULL_STEP(KK, ACC) { \
  constexpr int iA = PIF(2 * (KK)), jA = PJF(2 * (KK)); \
  constexpr int iB = PIF(2 * (KK) + 1), jB = PJF(2 * (KK) + 1); \
  float xxA = xr[iA] * xr[jA]; \
  float xxB = xr[iB] * xr[jB]; \
  float xx = selOdd ? xxB : xxA; \
  PACK_MFMA(xx * xsF[0], xx * xsF[1], xx * xsF[2], xx * xsF[3], \
            xx * xsF[4], xx * xsF[5], xx * xsF[6], xx * xsF[7], KK, ACC) \
}

#define H1_STEP(KK, ACC) { \
  constexpr int q = 4 * ((KK) - 18); \
  constexpr int i0 = PIH(q), j0 = PJH(q); \
  constexpr int i1 = PIH(q + 1), j1 = PJH(q + 1); \
  constexpr int i2 = PIH(q + 2), j2 = PJH(q + 2); \
  constexpr int i3 = PIH(q + 3), j3 = PJH(q + 3); \
  float xx0 = xr[i0] * xr[j0], xx1 = xr[i1] * xr[j1]; \
  float xx2 = xr[i2] * xr[j2], xx3 = xr[i3] * xr[j3]; \
  float xxE = selG1 ? xx1 : xx0; \
  float xxO = selG1 ? xx3 : xx2; \
  float xx = selOdd ? xxO : xxE; \
  PACK_MFMA(xx * xr[8], xx * xr[9], xx * xr[10], xx * xr[11], \
            xx * xr[12], xx * xr[13], xx * xr[14], xx * xr[15], KK, ACC) \
}

#define TAIL_STEP(KK, ACC) { \
  float mv[8]; \
  _Pragma("unroll") \
  for (int jj = 0; jj < 8; ++jj) { \
    int spec = sT[((KK) - 43) * 32 + g * 8 + jj]; \
    mv[jj] = sXw[spec & 31] * sXw[(spec >> 8) & 31]; \
  } \
  PACK_MFMA(mv[0], mv[1], mv[2], mv[3], mv[4], mv[5], mv[6], mv[7], KK, ACC) \
}

__global__ __launch_bounds__(512, 4) void k_main(const float* __restrict__ x,
                                                 const int* __restrict__ offs,
                                                 const int* __restrict__ list,
                                                 const unsigned short* __restrict__ W,
                                                 float* __restrict__ out) {
  __shared__ unsigned short sB[NSTEP * 512];   // 49152 B, K-major after staged swizzle
  __shared__ float sX[8][16][18];
  __shared__ int sT[160];
  int t = threadIdx.x;
  int w = t >> 6, lane = t & 63;
  int rc = lane & 15;
  int g = lane >> 4;
  bool selOdd = g >= 2;
  bool selG1 = g & 1;

  int ec = blockIdx.x;
  int e = ec >> 6, c = ec & 63;

  // stage W[ec] -> K-major LDS via pre-swizzled global source + linear LDS dest
  {
    const uint4* Wg4 = (const uint4*)(W + (size_t)ec * NROWS);
    uint4* sB4 = (uint4*)sB;
#pragma unroll
    for (int s2 = 0; s2 < 6; ++s2) {
      int p = t + 512 * s2;            // LDS unit = KK*64 + g*16 + o
      int KK = p >> 6, gg = (p >> 4) & 3, oo = p & 15;
      int G = oo * 192 + ((4 * KK + gg) ^ (oo & 7));
      __builtin_amdgcn_global_load_lds(
          (const __attribute__((address_space(1))) void*)(Wg4 + G),
          (__attribute__((address_space(3))) void*)(sB4 + w * 64 + 512 * s2),
          16, 0, 0);
    }
  }
  if (t < 160) {
    int r = t, a, b2;
    if (r < 136) { int p = r, i2 = 0; while (p >= 16 - i2) { p -= 16 - i2; ++i2; } a = i2; b2 = i2 + p; }
    else if (r < 152) { a = r - 136; b2 = 16; }
    else { a = 17; b2 = 17; }
    sT[r] = a | (b2 << 8);
  }
  __syncthreads();                     // drains vmcnt incl. global_load_lds

  float* sXw = &sX[w][rc][0];
  int off = offs[e], nb = offs[e + 1] - off;
  int nt = (nb + 15) >> 4;
  const char* bkL = (const char*)sB + lane * 16;   // conflict-free base

  for (int tile = w; tile < nt; tile += 8) {
    int m = tile * 16 + rc;
    int node = list[off + (m < nb ? m : nb - 1)];
    float xr[16];
    {
      const float4* xp = (const float4*)(x + ((size_t)node * NCH + c) * 16);
      float4 q0 = xp[0], q1 = xp[1], q2 = xp[2], q3 = xp[3];
      xr[0] = q0.x; xr[1] = q0.y; xr[2] = q0.z; xr[3] = q0.w;
      xr[4] = q1.x; xr[5] = q1.y; xr[6] = q1.z; xr[7] = q1.w;
      xr[8] = q2.x; xr[9] = q2.y; xr[10] = q2.z; xr[11] = q2.w;
      xr[12] = q3.x; xr[13] = q3.y; xr[14] = q3.z; xr[15] = q3.w;
    }
    float xsF[8];
#pragma unroll
    for (int j = 0; j < 8; ++j) xsF[j] = selG1 ? xr[8 + j] : xr[j];
    if (g == 0) {                      // publish row for tail steps (same-wave use only)
#pragma unroll
      for (int l = 0; l < 16; ++l) sXw[l] = xr[l];
      sXw[16] = 1.f; sXw[17] = 0.f;
    }

    float4v acc0 = {0.f, 0.f, 0.f, 0.f};
    float4v acc1 = {0.f, 0.f, 0.f, 0.f};
#define S2F(K) FULL_STEP(K, acc0) FULL_STEP((K) + 1, acc1)
#define S2H(K) H1_STEP(K, acc0) H1_STEP((K) + 1, acc1)
    S2F(0) S2F(2) S2F(4) S2F(6) S2F(8) S2F(10) S2F(12) S2F(14) S2F(16)
    S2H(18) S2H(20) S2H(22) S2H(24) S2H(26) S2H(28) S2H(30) S2H(32)
    S2H(34) S2H(36) S2H(38) S2H(40)
    H1_STEP(42, acc0)
    TAIL_STEP(43, acc1)
    TAIL_STEP(44, acc0) TAIL_STEP(45, acc1)
    TAIL_STEP(46, acc0) TAIL_STEP(47, acc1)
    float4v accs = acc0 + acc1;

#pragma unroll
    for (int r3 = 0; r3 < 4; ++r3) {
      int row = g * 4 + r3;
      int mrow = tile * 16 + row;
      if (mrow < nb) {
        int nd = __shfl(node, row);
        out[((size_t)nd * NCH + c) * 16 + rc] = accs[r3];
      }
    }
  }
}

extern "C" void kernel_launch(void* const* d_in, const int* in_sizes, int n_in,
                              void* d_out, int out_size, void* d_ws, size_t ws_size,
                              hipStream_t stream) {
  (void)in_sizes; (void)n_in; (void)out_size; (void)ws_size;
  const float* x   = (const float*)d_in[0];
  const int*   idx = (const int*)d_in[1];
  const float* w1  = (const float*)d_in[2];
  const float* w2  = (const float*)d_in[3];
  const float* w3  = (const float*)d_in[4];
  const float* U1  = (const float*)d_in[5];
  const float* U2  = (const float*)d_in[6];
  const float* U3  = (const float*)d_in[7];
  float* out = (float*)d_out;
  char* ws = (char*)d_ws;
  int* ws_offs = (int*)(ws + WS_OFFS);
  int* ws_list = (int*)(ws + WS_LIST);
  unsigned short* W = (unsigned short*)(ws + WS_W);

  hipLaunchKernelGGL(k_bgemm, dim3(961), dim3(256), 0, stream, U3, U2, U1, w3, w2, w1,
                     idx, W, ws_offs, ws_list);
  hipLaunchKernelGGL(k_main, dim3(640), dim3(512), 0, stream, x, ws_offs, ws_list, W, out);
}